// Round 5
// baseline (285.113 us; speedup 1.0000x reference)
//
#include <hip/hip_runtime.h>
#include <hip/hip_bf16.h>

#define N_B 4
#define SEQ 2048
#define EMB 1024
#define NH  16
#define HD  64

typedef __attribute__((ext_vector_type(8))) short bf16x8;   // 8 bf16 in 4 VGPRs
typedef __attribute__((ext_vector_type(4))) float f32x4;
typedef unsigned int u32;
typedef unsigned long long u64;
typedef unsigned short u16;

__device__ __forceinline__ void load_lds_16B(const void* g, void* lds) {
  __builtin_amdgcn_global_load_lds(
      (const __attribute__((address_space(1))) u32*)g,
      (__attribute__((address_space(3))) u32*)lds, 16, 0, 0);
}

// pack two f32 -> two bf16 (round-to-nearest via +0x8000 before truncate; ~3 VALU)
__device__ __forceinline__ u32 pk2(float a, float b) {
  u32 au = __float_as_uint(a) + 0x8000u;
  u32 bu = __float_as_uint(b) + 0x8000u;
  return (au >> 16) | (bu & 0xFFFF0000u);
}

// ---------------- mask -> bitmask, layout [n][kb][q] (contiguous in q) ----------------
__global__ __launch_bounds__(256) void pack_mask_k(const int* __restrict__ mask,
                                                   u64* __restrict__ bits) {
  int row = blockIdx.x;                // n*SEQ + q
  int n = row >> 11, q = row & 2047;
  int lane = threadIdx.x & 63;
  int wv = threadIdx.x >> 6;
  const int* m = mask + (size_t)row * SEQ;
  for (int w = wv; w < SEQ / 64; w += 4) {
    int v = m[w * 64 + lane];
    u64 bal = __ballot(v != 0);
    if (lane == 0) bits[((size_t)n * 32 + w) * 2048 + q] = bal;
  }
}

// ---------------- fused per-head projections (q/k/v in one launch) ----------------
__global__ __launch_bounds__(256) void project3_k(const float* __restrict__ xv,
                                                  const float* __restrict__ xk,
                                                  const float* __restrict__ xq,
                                                  const float* __restrict__ Wv,
                                                  const float* __restrict__ Wk,
                                                  const float* __restrict__ Wq,
                                                  __hip_bfloat16* __restrict__ ov,
                                                  __hip_bfloat16* __restrict__ ok,
                                                  __hip_bfloat16* __restrict__ oq,
                                                  float qscale) {
  __shared__ __align__(16) float Ws4[64 * 17 * 4];  // W rows as float4, padded
  __shared__ __align__(16) float xs[1024];
  int which = blockIdx.y;
  const float* x = (which == 0) ? xv : (which == 1) ? xk : xq;
  const float* W = (which == 0) ? Wv : (which == 1) ? Wk : Wq;
  __hip_bfloat16* out = (which == 0) ? ov : (which == 1) ? ok : oq;
  float scale = (which == 2) ? qscale : 1.0f;

  int t = threadIdx.x;
  int row = blockIdx.x;            // n*SEQ + l
  int n = row >> 11, l = row & 2047;
  const float4* W4 = (const float4*)W;
#pragma unroll
  for (int i = 0; i < 4; ++i) {
    int f4 = i * 256 + t;                 // f4 = d*16 + dd4
    int d = f4 >> 4, dd4 = f4 & 15;
    *(float4*)&Ws4[(d * 17 + dd4) * 4] = W4[f4];
  }
  float4 v = ((const float4*)(x + (size_t)row * EMB))[t];
  *(float4*)&xs[t * 4] = v;
  __syncthreads();
  int d = t & 63, wv = t >> 6;
  float s[4] = {0.f, 0.f, 0.f, 0.f};
#pragma unroll
  for (int dd4 = 0; dd4 < 16; ++dd4) {
    float4 wv4 = *(const float4*)&Ws4[(d * 17 + dd4) * 4];
#pragma unroll
    for (int i = 0; i < 4; ++i) {
      float4 xv4 = *(const float4*)&xs[(i * 4 + wv) * 64 + dd4 * 4];
      s[i] += xv4.x * wv4.x + xv4.y * wv4.y + xv4.z * wv4.z + xv4.w * wv4.w;
    }
  }
#pragma unroll
  for (int i = 0; i < 4; ++i) {
    int h = i * 4 + wv;
    out[((size_t)(n * NH + h) * SEQ + l) * HD + d] = __float2bfloat16(s[i] * scale);
  }
}

// ---------------- fp32 -> bf16 copy (Wo) ----------------
__global__ __launch_bounds__(256) void cvt_bf16_k(const float* __restrict__ in,
                                                  __hip_bfloat16* __restrict__ out) {
  int i = (blockIdx.x * 256 + threadIdx.x) * 4;
  float4 v = *(const float4*)(in + i);
  out[i + 0] = __float2bfloat16(v.x);
  out[i + 1] = __float2bfloat16(v.y);
  out[i + 2] = __float2bfloat16(v.z);
  out[i + 3] = __float2bfloat16(v.w);
}

// ---------------- V transpose: vp[nh][key][d] -> vT[nh][d][key] ----------------
__global__ __launch_bounds__(256) void transpose_v_k(const __hip_bfloat16* __restrict__ vp,
                                                     __hip_bfloat16* __restrict__ vT) {
  __shared__ __align__(16) u16 Ls[64 * 64];   // [key][d], XOR-swizzled 16B chunks
  int t = threadIdx.x;
  int kt = blockIdx.x, nh = blockIdx.y;
  const u16* src = (const u16*)(vp + ((size_t)nh * SEQ + kt * 64) * HD);
#pragma unroll
  for (int p = 0; p < 2; ++p) {
    int key = p * 32 + (t >> 3);
    int dc = t & 7;                         // 16B chunk within row
    uint4 vv = *(const uint4*)(src + key * 64 + dc * 8);
    *(uint4*)((char*)Ls + key * 128 + ((dc ^ (key & 7)) * 16)) = vv;
  }
  __syncthreads();
  u16* dst = (u16*)(vT + (size_t)nh * HD * SEQ);
#pragma unroll
  for (int p = 0; p < 2; ++p) {
    int d = p * 32 + (t >> 3);
    int kc = t & 7;                         // key chunk (8 keys)
    union { u16 s[8]; uint4 v4; } u;
#pragma unroll
    for (int j = 0; j < 8; ++j) {
      int key = kc * 8 + j;
      u.s[j] = *(const u16*)((const char*)Ls + key * 128 + (((d >> 3) ^ (key & 7)) * 16) + (d & 7) * 2);
    }
    *(uint4*)(dst + (size_t)d * SEQ + kt * 64 + kc * 8) = u.v4;
  }
}

// ---------------- flash attention (swapped-operand S^T, seeded-accumulator softmax) ----------------
// Q pre-scaled by (1/sqrt(EMB))*log2(e). Lane owns q = qb*64 + w*16 + l15.
// QK MFMA C-in seeded with (masked ? -1e30 : -m): after MFMA, sf = s-m with mask
// folded in; exp2(sf) underflows to 0 for masked. Running max starts at 0
// (upper-bound reference; exact online softmax).
__global__ __launch_bounds__(256) void attn_k(const __hip_bfloat16* __restrict__ qp,
                                              const __hip_bfloat16* __restrict__ kp,
                                              const __hip_bfloat16* __restrict__ vT,
                                              const u64* __restrict__ mbits,
                                              __hip_bfloat16* __restrict__ obuf) {
  __shared__ __align__(16) __hip_bfloat16 Kt[64 * 64];       // [key][kdim] swz; P strip after QK
  __shared__ __align__(16) __hip_bfloat16 Vt[64 * 64];       // [d][key]   swz
  int t = threadIdx.x, lane = t & 63, w = t >> 6;
  int qb = blockIdx.x;
  int nh = blockIdx.y;
  int n = nh >> 4, h = nh & 15;
  const __hip_bfloat16* Qg = qp + ((size_t)nh * SEQ + qb * 64) * HD;
  const char* Kg = (const char*)(kp + (size_t)nh * SEQ * HD);
  const char* Vg = (const char*)(vT + (size_t)nh * HD * SEQ);
  int l15 = lane & 15, l4 = lane >> 4;
  int e7 = l15 & 7;

  int srow = t >> 3;
  int schunk = (t & 7) ^ (srow & 7);
  int soffA = srow * 128 + schunk * 16;

  // Q B-frag: col=l15 (q=w*16+l15), k = 32c + l4*8 + j
  bf16x8 qf[2];
#pragma unroll
  for (int c = 0; c < 2; ++c)
    qf[c] = *(const bf16x8*)(Qg + (size_t)(w * 16 + l15) * HD + c * 32 + l4 * 8);

  const bf16x8 ones = {(short)0x3F80, (short)0x3F80, (short)0x3F80, (short)0x3F80,
                       (short)0x3F80, (short)0x3F80, (short)0x3F80, (short)0x3F80};

  f32x4 of[4];
#pragma unroll
  for (int dt = 0; dt < 4; ++dt)
#pragma unroll
    for (int j = 0; j < 4; ++j) of[dt][j] = 0.f;
  float negm = 0.f, lrow = 0.f;     // running max m starts at 0 (upper bound)

  int q = qb * 64 + w * 16 + l15;

  // hoisted LDS byte offsets
  int prow_b = (w * 16 + l15) * 128;            // wave-exclusive P strip rows
  int pw[4], pr[2];
#pragma unroll
  for (int ct = 0; ct < 4; ++ct)
    pw[ct] = prow_b + (((2 * ct + (l4 >> 1)) ^ e7) * 16) + (l4 & 1) * 8;
#pragma unroll
  for (int kc = 0; kc < 2; ++kc)
    pr[kc] = prow_b + (((4 * kc + l4) ^ e7) * 16);

  // incremental global pointers
  const char* gk = Kg + soffA;
  const char* gv = Vg + (size_t)srow * 4096 + (size_t)schunk * 16;
  const u64* mptr = mbits + (size_t)n * 32 * 2048 + q;
  char* lk = (char*)Kt + w * 1024;
  char* lv = (char*)Vt + w * 1024;

  for (int kt = 0; kt < SEQ / 64; ++kt) {
    __syncthreads();                             // A: prev-iter LDS reads done
    load_lds_16B(gk, lk);
    load_lds_16B(gk + 4096, lk + 4096);
    load_lds_16B(gv, lv);
    load_lds_16B(gv + 32 * 4096, lv + 4096);
    u64 mw = *mptr;                              // 1 word per lane (its q)
    gk += 8192; gv += 128; mptr += 2048;
    asm volatile("s_waitcnt vmcnt(0)" ::: "memory");
    __syncthreads();                             // B: tiles staged

    // ---- seed C-in with mask + running max
    u64 m4 = mw >> (l4 * 4);
    u32 c0 = (u32)m4, c1 = (u32)(m4 >> 32);
    f32x4 sf[4];
#pragma unroll
    for (int ct = 0; ct < 4; ++ct) {
      u32 sel = (ct & 2) ? c1 : c0;
      u32 base = (ct & 1) ? 0x10000u : 1u;
#pragma unroll
      for (int r = 0; r < 4; ++r)
        sf[ct][r] = (sel & (base << r)) ? negm : -1e30f;
    }
    // ---- S^T = K Q^T: A = K-frag (rows=keys), B = Q-frag (cols=q)
#pragma unroll
    for (int c = 0; c < 2; ++c) {
#pragma unroll
      for (int ct = 0; ct < 4; ++ct) {
        int krow = ct * 16 + l15;
        bf16x8 ak = *(const bf16x8*)((const char*)Kt + krow * 128 + (((c * 4 + l4) ^ e7) * 16));
        sf[ct] = __builtin_amdgcn_mfma_f32_16x16x32_bf16(ak, qf[c], sf[ct], 0, 0, 0);
      }
    }

    // ---- tmax (pairwise tree; sf already = s - m, masked = -1e30)
    float tmax = fmaxf(
        fmaxf(fmaxf(fmaxf(sf[0][0], sf[0][1]), fmaxf(sf[0][2], sf[0][3])),
              fmaxf(fmaxf(sf[1][0], sf[1][1]), fmaxf(sf[1][2], sf[1][3]))),
        fmaxf(fmaxf(fmaxf(sf[2][0], sf[2][1]), fmaxf(sf[2][2], sf[2][3])),
              fmaxf(fmaxf(sf[3][0], sf[3][1]), fmaxf(sf[3][2], sf[3][3]))));
    if (__any(tmax > 0.f)) {                     // new max somewhere in wave
      float d = fmaxf(tmax, __shfl_xor(tmax, 16));
      d = fmaxf(d, __shfl_xor(d, 32));
      d = fmaxf(d, 0.f);                         // per-q delta (0 if no new max)
      float corr = __builtin_amdgcn_exp2f(-d);
      negm -= d;
      lrow *= corr;
#pragma unroll
      for (int dt = 0; dt < 4; ++dt)
#pragma unroll
        for (int r = 0; r < 4; ++r) of[dt][r] *= corr;
#pragma unroll
      for (int ct = 0; ct < 4; ++ct)
#pragma unroll
        for (int r = 0; r < 4; ++r) sf[ct][r] -= d;
    }
    // ---- p = exp2(sf) (masked underflow to 0), pack to bf16 pairs in regs
    uint2 pv2[4];
#pragma unroll
    for (int ct = 0; ct < 4; ++ct) {
      float e0 = __builtin_amdgcn_exp2f(sf[ct][0]);
      float e1 = __builtin_amdgcn_exp2f(sf[ct][1]);
      float e2 = __builtin_amdgcn_exp2f(sf[ct][2]);
      float e3 = __builtin_amdgcn_exp2f(sf[ct][3]);
      pv2[ct].x = pk2(e0, e1);
      pv2[ct].y = pk2(e2, e3);
    }
    __syncthreads();                             // C: all QK reads of Kt complete
#pragma unroll
    for (int ct = 0; ct < 4; ++ct)
      *(uint2*)((char*)Kt + pw[ct]) = pv2[ct];
    // ---- B-frags for PV + row-sum via MFMA
    bf16x8 pb[2];
#pragma unroll
    for (int kc = 0; kc < 2; ++kc)
      pb[kc] = *(const bf16x8*)((const char*)Kt + pr[kc]);
    f32x4 rs = {0.f, 0.f, 0.f, 0.f};
    rs = __builtin_amdgcn_mfma_f32_16x16x32_bf16(ones, pb[0], rs, 0, 0, 0);
    rs = __builtin_amdgcn_mfma_f32_16x16x32_bf16(ones, pb[1], rs, 0, 0, 0);
    lrow += rs[0];
    // ---- O^T += V^T P : A = V^T-frag (rows=d), B = P-frag (cols=q)
#pragma unroll
    for (int kc = 0; kc < 2; ++kc) {
#pragma unroll
      for (int dt = 0; dt < 4; ++dt) {
        int vrow = dt * 16 + l15;
        bf16x8 av = *(const bf16x8*)((const char*)Vt + vrow * 128 + (((kc * 4 + l4) ^ e7) * 16));
        of[dt] = __builtin_amdgcn_mfma_f32_16x16x32_bf16(av, pb[kc], of[dt], 0, 0, 0);
      }
    }
  }
  // ---- epilogue: lane owns q; d = 16dt + 4*l4 + r (8B packed stores)
  float inv = 1.f / lrow;
  size_t obase = ((size_t)n * SEQ + q) * EMB + h * HD;
#pragma unroll
  for (int dt = 0; dt < 4; ++dt) {
    uint2 v2 = {pk2(of[dt][0] * inv, of[dt][1] * inv),
                pk2(of[dt][2] * inv, of[dt][3] * inv)};
    *(uint2*)(obuf + obase + dt * 16 + l4 * 4) = v2;
  }
}

// ---------------- output GEMM ----------------
__global__ __launch_bounds__(256) void out_gemm_k(const __hip_bfloat16* __restrict__ A,
                                                  const __hip_bfloat16* __restrict__ Bw,
                                                  const float* __restrict__ bias,
                                                  float* __restrict__ Y) {
  __shared__ __align__(16) __hip_bfloat16 As[128 * 32];
  __shared__ __align__(16) __hip_bfloat16 Bs[128 * 32];
  int t = threadIdx.x, lane = t & 63, w = t >> 6;
  int l15 = lane & 15, l4 = lane >> 4;
  int bm = blockIdx.x * 128, bn = blockIdx.y * 128;
  int wr = w >> 1, wc = w & 1;
  f32x4 acc[4][4];
#pragma unroll
  for (int m = 0; m < 4; ++m)
#pragma unroll
    for (int nn = 0; nn < 4; ++nn)
#pragma unroll
      for (int j = 0; j < 4; ++j) acc[m][nn][j] = 0.f;

  int o = t * 8;
  int srow = o >> 5, scol = o & 31;
  for (int kt = 0; kt < 32; ++kt) {
    __syncthreads();
    {
      const char* ga = (const char*)(A + (size_t)(bm + srow) * 1024 + kt * 32 + scol);
      char* la = (char*)As + w * 1024;
      load_lds_16B(ga, la);
      load_lds_16B((const char*)(A + (size_t)(bm + srow + 64) * 1024 + kt * 32 + scol), la + 4096);
      const char* gb = (const char*)(Bw + (size_t)(bn + srow) * 1024 + kt * 32 + scol);
      char* lb = (char*)Bs + w * 1024;
      load_lds_16B(gb, lb);
      load_lds_16B((const char*)(Bw + (size_t)(bn + srow + 64) * 1024 + kt * 32 + scol), lb + 4096);
    }
    asm volatile("s_waitcnt vmcnt(0)" ::: "memory");
    __syncthreads();
    bf16x8 af[4], bfr[4];
#pragma unroll
    for (int m = 0; m < 4; ++m)
      af[m] = *(const bf16x8*)((const char*)As + (wr * 64 + m * 16 + l15) * 64 + l4 * 16);
#pragma unroll
    for (int nn = 0; nn < 4; ++nn)
      bfr[nn] = *(const bf16x8*)((const char*)Bs + (wc * 64 + nn * 16 + l15) * 64 + l4 * 16);
#pragma unroll
    for (int m = 0; m < 4; ++m)
#pragma unroll
      for (int nn = 0; nn < 4; ++nn)
        acc[m][nn] = __builtin_amdgcn_mfma_f32_16x16x32_bf16(af[m], bfr[nn], acc[m][nn], 0, 0, 0);
  }
#pragma unroll
  for (int m = 0; m < 4; ++m)
#pragma unroll
    for (int nn = 0; nn < 4; ++nn)
#pragma unroll
      for (int r = 0; r < 4; ++r) {
        int row = bm + wr * 64 + m * 16 + l4 * 4 + r;
        int col = bn + wc * 64 + nn * 16 + l15;
        Y[(size_t)row * 1024 + col] = acc[m][nn][r] + bias[col];
      }
}

extern "C" void kernel_launch(void* const* d_in, const int* in_sizes, int n_in,
                              void* d_out, int out_size, void* d_ws, size_t ws_size,
                              hipStream_t stream) {
  const float* values  = (const float*)d_in[0];
  const float* keys    = (const float*)d_in[1];
  const float* queries = (const float*)d_in[2];
  const int*   mask    = (const int*)d_in[3];
  const float* Wv      = (const float*)d_in[4];
  const float* Wk      = (const float*)d_in[5];
  const float* Wq      = (const float*)d_in[6];
  const float* Wo      = (const float*)d_in[7];
  const float* bo      = (const float*)d_in[8];
  float* out = (float*)d_out;

  char* ws = (char*)d_ws;
  __hip_bfloat16* qp   = (__hip_bfloat16*)(ws);
  __hip_bfloat16* kp   = (__hip_bfloat16*)(ws + (size_t)16 * 1024 * 1024);
  __hip_bfloat16* vp   = (__hip_bfloat16*)(ws + (size_t)32 * 1024 * 1024);
  __hip_bfloat16* obuf = (__hip_bfloat16*)(ws + (size_t)48 * 1024 * 1024);
  u64*            mbts = (u64*)           (ws + (size_t)64 * 1024 * 1024);
  __hip_bfloat16* wob  = (__hip_bfloat16*)(ws + (size_t)66 * 1024 * 1024);
  __hip_bfloat16* vTp  = (__hip_bfloat16*)(ws + (size_t)80 * 1024 * 1024);

  // Q pre-scale: (1/sqrt(EMB)) * log2(e) so attn softmax runs in exp2 domain
  const float qscale = 0.03125f * 1.44269504088896340736f;

  pack_mask_k<<<dim3(N_B * SEQ), 256, 0, stream>>>(mask, mbts);
  project3_k<<<dim3(N_B * SEQ, 3), 256, 0, stream>>>(values, keys, queries,
                                                     Wv, Wk, Wq, vp, kp, qp, qscale);
  transpose_v_k<<<dim3(SEQ / 64, N_B * NH), 256, 0, stream>>>(vp, vTp);
  cvt_bf16_k<<<dim3(1024), 256, 0, stream>>>(Wo, wob);
  attn_k<<<dim3(SEQ / 64, N_B * NH), 256, 0, stream>>>(qp, kp, vTp, mbts, obuf);
  out_gemm_k<<<dim3(64, 8), 256, 0, stream>>>(obuf, wob, bo, out);
}

// Round 6
// 277.173 us; speedup vs baseline: 1.0286x; 1.0286x over previous
//
#include <hip/hip_runtime.h>
#include <hip/hip_bf16.h>

#define N_B 4
#define SEQ 2048
#define EMB 1024
#define NH  16
#define HD  64

typedef __attribute__((ext_vector_type(8))) short bf16x8;   // 8 bf16 in 4 VGPRs
typedef __attribute__((ext_vector_type(4))) short bf16x4;   // 4 bf16 in 2 VGPRs
typedef __attribute__((ext_vector_type(4))) float f32x4;
typedef unsigned int u32;
typedef unsigned long long u64;
typedef unsigned short u16;

#if __has_builtin(__builtin_amdgcn_mfma_f32_16x16x16bf16_1k)
#define HAS_MFMA16 1
#else
#define HAS_MFMA16 0
#endif

__device__ __forceinline__ void load_lds_16B(const void* g, void* lds) {
  __builtin_amdgcn_global_load_lds(
      (const __attribute__((address_space(1))) u32*)g,
      (__attribute__((address_space(3))) u32*)lds, 16, 0, 0);
}

// pack two f32 -> two bf16 (round-to-nearest via +0x8000 before truncate)
__device__ __forceinline__ u32 pk2(float a, float b) {
  u32 au = __float_as_uint(a) + 0x8000u;
  u32 bu = __float_as_uint(b) + 0x8000u;
  return (au >> 16) | (bu & 0xFFFF0000u);
}

// ---------------- mask -> bitmask, layout [n][kb][q] (contiguous in q) ----------------
__global__ __launch_bounds__(256) void pack_mask_k(const int* __restrict__ mask,
                                                   u64* __restrict__ bits) {
  int row = blockIdx.x;                // n*SEQ + q
  int n = row >> 11, q = row & 2047;
  int lane = threadIdx.x & 63;
  int wv = threadIdx.x >> 6;
  const int* m = mask + (size_t)row * SEQ;
  for (int w = wv; w < SEQ / 64; w += 4) {
    int v = m[w * 64 + lane];
    u64 bal = __ballot(v != 0);
    if (lane == 0) bits[((size_t)n * 32 + w) * 2048 + q] = bal;
  }
}

// ---------------- fused per-head projections (q/k/v in one launch) ----------------
__global__ __launch_bounds__(256) void project3_k(const float* __restrict__ xv,
                                                  const float* __restrict__ xk,
                                                  const float* __restrict__ xq,
                                                  const float* __restrict__ Wv,
                                                  const float* __restrict__ Wk,
                                                  const float* __restrict__ Wq,
                                                  __hip_bfloat16* __restrict__ ov,
                                                  __hip_bfloat16* __restrict__ ok,
                                                  __hip_bfloat16* __restrict__ oq,
                                                  float qscale) {
  __shared__ __align__(16) float Ws4[64 * 17 * 4];  // W rows as float4, padded
  __shared__ __align__(16) float xs[1024];
  int which = blockIdx.y;
  const float* x = (which == 0) ? xv : (which == 1) ? xk : xq;
  const float* W = (which == 0) ? Wv : (which == 1) ? Wk : Wq;
  __hip_bfloat16* out = (which == 0) ? ov : (which == 1) ? ok : oq;
  float scale = (which == 2) ? qscale : 1.0f;

  int t = threadIdx.x;
  int row = blockIdx.x;            // n*SEQ + l
  int n = row >> 11, l = row & 2047;
  const float4* W4 = (const float4*)W;
#pragma unroll
  for (int i = 0; i < 4; ++i) {
    int f4 = i * 256 + t;                 // f4 = d*16 + dd4
    int d = f4 >> 4, dd4 = f4 & 15;
    *(float4*)&Ws4[(d * 17 + dd4) * 4] = W4[f4];
  }
  float4 v = ((const float4*)(x + (size_t)row * EMB))[t];
  *(float4*)&xs[t * 4] = v;
  __syncthreads();
  int d = t & 63, wv = t >> 6;
  float s[4] = {0.f, 0.f, 0.f, 0.f};
#pragma unroll
  for (int dd4 = 0; dd4 < 16; ++dd4) {
    float4 wv4 = *(const float4*)&Ws4[(d * 17 + dd4) * 4];
#pragma unroll
    for (int i = 0; i < 4; ++i) {
      float4 xv4 = *(const float4*)&xs[(i * 4 + wv) * 64 + dd4 * 4];
      s[i] += xv4.x * wv4.x + xv4.y * wv4.y + xv4.z * wv4.z + xv4.w * wv4.w;
    }
  }
#pragma unroll
  for (int i = 0; i < 4; ++i) {
    int h = i * 4 + wv;
    out[((size_t)(n * NH + h) * SEQ + l) * HD + d] = __float2bfloat16(s[i] * scale);
  }
}

// ---------------- fp32 -> bf16 copy (Wo) ----------------
__global__ __launch_bounds__(256) void cvt_bf16_k(const float* __restrict__ in,
                                                  __hip_bfloat16* __restrict__ out) {
  int i = (blockIdx.x * 256 + threadIdx.x) * 4;
  float4 v = *(const float4*)(in + i);
  out[i + 0] = __float2bfloat16(v.x);
  out[i + 1] = __float2bfloat16(v.y);
  out[i + 2] = __float2bfloat16(v.z);
  out[i + 3] = __float2bfloat16(v.w);
}

// ---------------- V transpose: vp[nh][key][d] -> vT[nh][d][key] ----------------
__global__ __launch_bounds__(256) void transpose_v_k(const __hip_bfloat16* __restrict__ vp,
                                                     __hip_bfloat16* __restrict__ vT) {
  __shared__ __align__(16) u16 Ls[64 * 64];   // [key][d], XOR-swizzled 16B chunks
  int t = threadIdx.x;
  int kt = blockIdx.x, nh = blockIdx.y;
  const u16* src = (const u16*)(vp + ((size_t)nh * SEQ + kt * 64) * HD);
#pragma unroll
  for (int p = 0; p < 2; ++p) {
    int key = p * 32 + (t >> 3);
    int dc = t & 7;                         // 16B chunk within row
    uint4 vv = *(const uint4*)(src + key * 64 + dc * 8);
    *(uint4*)((char*)Ls + key * 128 + ((dc ^ (key & 7)) * 16)) = vv;
  }
  __syncthreads();
  u16* dst = (u16*)(vT + (size_t)nh * HD * SEQ);
#pragma unroll
  for (int p = 0; p < 2; ++p) {
    int d = p * 32 + (t >> 3);
    int kc = t & 7;                         // key chunk (8 keys)
    union { u16 s[8]; uint4 v4; } u;
#pragma unroll
    for (int j = 0; j < 8; ++j) {
      int key = kc * 8 + j;
      u.s[j] = *(const u16*)((const char*)Ls + key * 128 + (((d >> 3) ^ (key & 7)) * 16) + (d & 7) * 2);
    }
    *(uint4*)(dst + (size_t)d * SEQ + kt * 64 + kc * 8) = u.v4;
  }
}

// ---------------- flash attention (swapped-operand S^T; register-resident P) ----------------
// Q pre-scaled by (1/sqrt(EMB))*log2(e). Lane owns q = qb*64 + w*16 + l15.
// QK (16x16x32, swapped) leaves S^T[key=ct*16+4*l4+r][q=l15] in lane regs.
// That layout IS the B-fragment of v_mfma_f32_16x16x16_bf16 (k=4*l4+j, col=l15),
// so P feeds PV and the row-sum MFMA directly from registers: no P LDS
// round-trip, no third barrier.
__global__ __launch_bounds__(256) void attn_k(const __hip_bfloat16* __restrict__ qp,
                                              const __hip_bfloat16* __restrict__ kp,
                                              const __hip_bfloat16* __restrict__ vT,
                                              const u64* __restrict__ mbits,
                                              __hip_bfloat16* __restrict__ obuf) {
  __shared__ __align__(16) __hip_bfloat16 Kt[64 * 64];       // [key][kdim] swz
  __shared__ __align__(16) __hip_bfloat16 Vt[64 * 64];       // [d][key]   swz
#if !HAS_MFMA16
  __shared__ __align__(16) __hip_bfloat16 Pl[64 * 64];       // fallback P buffer
#endif
  int t = threadIdx.x, lane = t & 63, w = t >> 6;
  int qb = blockIdx.x;
  int nh = blockIdx.y;
  int n = nh >> 4, h = nh & 15;
  const __hip_bfloat16* Qg = qp + ((size_t)nh * SEQ + qb * 64) * HD;
  const char* Kg = (const char*)(kp + (size_t)nh * SEQ * HD);
  const char* Vg = (const char*)(vT + (size_t)nh * HD * SEQ);
  int l15 = lane & 15, l4 = lane >> 4;
  int e7 = l15 & 7;

  int srow = t >> 3;
  int schunk = (t & 7) ^ (srow & 7);
  int soffA = srow * 128 + schunk * 16;

  // Q B-frag: col=l15 (q=w*16+l15), k = 32c + l4*8 + j
  bf16x8 qf[2];
#pragma unroll
  for (int c = 0; c < 2; ++c)
    qf[c] = *(const bf16x8*)(Qg + (size_t)(w * 16 + l15) * HD + c * 32 + l4 * 8);

  f32x4 of[4];
#pragma unroll
  for (int dt = 0; dt < 4; ++dt)
#pragma unroll
    for (int j = 0; j < 4; ++j) of[dt][j] = 0.f;
  float mrow = -1e20f, lrow = 0.f;

  int q = qb * 64 + w * 16 + l15;

  // incremental global pointers
  const char* gk = Kg + soffA;
  const char* gv = Vg + (size_t)srow * 4096 + (size_t)schunk * 16;
  const u64* mptr = mbits + (size_t)n * 32 * 2048 + q;
  char* lk = (char*)Kt + w * 1024;
  char* lv = (char*)Vt + w * 1024;

#if HAS_MFMA16
  const bf16x4 ones4 = {(short)0x3F80, (short)0x3F80, (short)0x3F80, (short)0x3F80};
  // hoisted Vt byte offsets for PV A-frags (b64): [dt][ct]
  // V^T[d = dt*16+l15][key = ct*16 + 4*l4 + j], j=0..3
  // global chunk = 2ct + (l4>>1); swz with row e7; +8B if l4 odd
  int voff[4];
#pragma unroll
  for (int ct = 0; ct < 4; ++ct)
    voff[ct] = (((2 * ct + (l4 >> 1)) ^ e7) * 16) + (l4 & 1) * 8;
#else
  const bf16x8 ones = {(short)0x3F80, (short)0x3F80, (short)0x3F80, (short)0x3F80,
                       (short)0x3F80, (short)0x3F80, (short)0x3F80, (short)0x3F80};
  int prow_b = (w * 16 + l15) * 128;
  int pw[4], pr[2];
#pragma unroll
  for (int ct = 0; ct < 4; ++ct)
    pw[ct] = prow_b + (((2 * ct + (l4 >> 1)) ^ e7) * 16) + (l4 & 1) * 8;
#pragma unroll
  for (int kc = 0; kc < 2; ++kc)
    pr[kc] = prow_b + (((4 * kc + l4) ^ e7) * 16);
#endif

  for (int kt = 0; kt < SEQ / 64; ++kt) {
    __syncthreads();                             // A: prev-iter LDS reads done
    load_lds_16B(gk, lk);
    load_lds_16B(gk + 4096, lk + 4096);
    load_lds_16B(gv, lv);
    load_lds_16B(gv + 32 * 4096, lv + 4096);
    u64 mw = *mptr;                              // 1 word per lane (its q)
    gk += 8192; gv += 128; mptr += 2048;
    asm volatile("s_waitcnt vmcnt(0)" ::: "memory");
    __syncthreads();                             // B: tiles staged

    // ---- S^T = K Q^T: A = K-frag (rows=keys), B = Q-frag (cols=q)
    f32x4 sf[4];
#pragma unroll
    for (int ct = 0; ct < 4; ++ct)
#pragma unroll
      for (int j = 0; j < 4; ++j) sf[ct][j] = 0.f;
#pragma unroll
    for (int c = 0; c < 2; ++c) {
#pragma unroll
      for (int ct = 0; ct < 4; ++ct) {
        int krow = ct * 16 + l15;
        bf16x8 ak = *(const bf16x8*)((const char*)Kt + krow * 128 + (((c * 4 + l4) ^ e7) * 16));
        sf[ct] = __builtin_amdgcn_mfma_f32_16x16x32_bf16(ak, qf[c], sf[ct], 0, 0, 0);
      }
    }

    // ---- online softmax (scalar per lane; max over unmasked superset, exact)
    float tmax = fmaxf(
        fmaxf(fmaxf(fmaxf(sf[0][0], sf[0][1]), fmaxf(sf[0][2], sf[0][3])),
              fmaxf(fmaxf(sf[1][0], sf[1][1]), fmaxf(sf[1][2], sf[1][3]))),
        fmaxf(fmaxf(fmaxf(sf[2][0], sf[2][1]), fmaxf(sf[2][2], sf[2][3])),
              fmaxf(fmaxf(sf[3][0], sf[3][1]), fmaxf(sf[3][2], sf[3][3]))));
    if (__any(tmax > mrow)) {
      float tm = tmax;
      tm = fmaxf(tm, __shfl_xor(tm, 16));
      tm = fmaxf(tm, __shfl_xor(tm, 32));
      float mn = fmaxf(mrow, tm);
      float corr = __builtin_amdgcn_exp2f(mrow - mn);
      mrow = mn;
      lrow *= corr;
#pragma unroll
      for (int dt = 0; dt < 4; ++dt)
#pragma unroll
        for (int r = 0; r < 4; ++r) of[dt][r] *= corr;
    }
    // ---- p = exp2(s - m), mask-zero (bit 16ct + 4*l4 + r of mw), pack to bf16
    u64 m4 = mw >> (l4 * 4);
    u32 c0 = (u32)m4, c1 = (u32)(m4 >> 32);
#if HAS_MFMA16
    bf16x4 pbq[4];
#else
    uint2 pv2[4];
#endif
#pragma unroll
    for (int ct = 0; ct < 4; ++ct) {
      u32 sel = (ct & 2) ? c1 : c0;
      u32 base = (ct & 1) ? 0x10000u : 1u;
      float p0 = __builtin_amdgcn_exp2f(sf[ct][0] - mrow);
      float p1 = __builtin_amdgcn_exp2f(sf[ct][1] - mrow);
      float p2 = __builtin_amdgcn_exp2f(sf[ct][2] - mrow);
      float p3 = __builtin_amdgcn_exp2f(sf[ct][3] - mrow);
      p0 = (sel & (base << 0)) ? p0 : 0.f;
      p1 = (sel & (base << 1)) ? p1 : 0.f;
      p2 = (sel & (base << 2)) ? p2 : 0.f;
      p3 = (sel & (base << 3)) ? p3 : 0.f;
      union { u32 u[2]; bf16x4 s; uint2 v2; } pu;
      pu.u[0] = pk2(p0, p1);
      pu.u[1] = pk2(p2, p3);
#if HAS_MFMA16
      pbq[ct] = pu.s;
#else
      pv2[ct] = pu.v2;
#endif
    }
#if HAS_MFMA16
    // ---- row-sum via K=16 MFMA on register P (matrix pipe is idle)
    f32x4 rs = {0.f, 0.f, 0.f, 0.f};
#pragma unroll
    for (int ct = 0; ct < 4; ++ct)
      rs = __builtin_amdgcn_mfma_f32_16x16x16bf16_1k(ones4, pbq[ct], rs, 0, 0, 0);
    lrow += rs[0];
    // ---- O^T += V^T P : 16x A = V^T b64 frags, B = register P frags
#pragma unroll
    for (int dt = 0; dt < 4; ++dt) {
      int vrow_b = (dt * 16 + l15) * 128;
#pragma unroll
      for (int ct = 0; ct < 4; ++ct) {
        bf16x4 av = *(const bf16x4*)((const char*)Vt + vrow_b + voff[ct]);
        of[dt] = __builtin_amdgcn_mfma_f32_16x16x16bf16_1k(av, pbq[ct], of[dt], 0, 0, 0);
      }
    }
#else
    // ---- fallback: P through LDS (R4 path)
    __syncthreads();
#pragma unroll
    for (int ct = 0; ct < 4; ++ct)
      *(uint2*)((char*)Pl + pw[ct]) = pv2[ct];
    bf16x8 pb[2];
#pragma unroll
    for (int kc = 0; kc < 2; ++kc)
      pb[kc] = *(const bf16x8*)((const char*)Pl + pr[kc]);
    f32x4 rs = {0.f, 0.f, 0.f, 0.f};
    rs = __builtin_amdgcn_mfma_f32_16x16x32_bf16(ones, pb[0], rs, 0, 0, 0);
    rs = __builtin_amdgcn_mfma_f32_16x16x32_bf16(ones, pb[1], rs, 0, 0, 0);
    lrow += rs[0];
#pragma unroll
    for (int kc = 0; kc < 2; ++kc) {
#pragma unroll
      for (int dt = 0; dt < 4; ++dt) {
        int vrow = dt * 16 + l15;
        bf16x8 av = *(const bf16x8*)((const char*)Vt + vrow * 128 + (((kc * 4 + l4) ^ e7) * 16));
        of[dt] = __builtin_amdgcn_mfma_f32_16x16x32_bf16(av, pb[kc], of[dt], 0, 0, 0);
      }
    }
#endif
  }
  // ---- epilogue: lane owns q; d = 16dt + 4*l4 + r (8B packed stores)
  float inv = 1.f / lrow;
  size_t obase = ((size_t)n * SEQ + q) * EMB + h * HD;
#pragma unroll
  for (int dt = 0; dt < 4; ++dt) {
    uint2 v2 = {pk2(of[dt][0] * inv, of[dt][1] * inv),
                pk2(of[dt][2] * inv, of[dt][3] * inv)};
    *(uint2*)(obuf + obase + dt * 16 + l4 * 4) = v2;
  }
}

// ---------------- output GEMM ----------------
__global__ __launch_bounds__(256) void out_gemm_k(const __hip_bfloat16* __restrict__ A,
                                                  const __hip_bfloat16* __restrict__ Bw,
                                                  const float* __restrict__ bias,
                                                  float* __restrict__ Y) {
  __shared__ __align__(16) __hip_bfloat16 As[128 * 32];
  __shared__ __align__(16) __hip_bfloat16 Bs[128 * 32];
  int t = threadIdx.x, lane = t & 63, w = t >> 6;
  int l15 = lane & 15, l4 = lane >> 4;
  int bm = blockIdx.x * 128, bn = blockIdx.y * 128;
  int wr = w >> 1, wc = w & 1;
  f32x4 acc[4][4];
#pragma unroll
  for (int m = 0; m < 4; ++m)
#pragma unroll
    for (int nn = 0; nn < 4; ++nn)
#pragma unroll
      for (int j = 0; j < 4; ++j) acc[m][nn][j] = 0.f;

  int o = t * 8;
  int srow = o >> 5, scol = o & 31;
  for (int kt = 0; kt < 32; ++kt) {
    __syncthreads();
    {
      const char* ga = (const char*)(A + (size_t)(bm + srow) * 1024 + kt * 32 + scol);
      char* la = (char*)As + w * 1024;
      load_lds_16B(ga, la);
      load_lds_16B((const char*)(A + (size_t)(bm + srow + 64) * 1024 + kt * 32 + scol), la + 4096);
      const char* gb = (const char*)(Bw + (size_t)(bn + srow) * 1024 + kt * 32 + scol);
      char* lb = (char*)Bs + w * 1024;
      load_lds_16B(gb, lb);
      load_lds_16B((const char*)(Bw + (size_t)(bn + srow + 64) * 1024 + kt * 32 + scol), lb + 4096);
    }
    asm volatile("s_waitcnt vmcnt(0)" ::: "memory");
    __syncthreads();
    bf16x8 af[4], bfr[4];
#pragma unroll
    for (int m = 0; m < 4; ++m)
      af[m] = *(const bf16x8*)((const char*)As + (wr * 64 + m * 16 + l15) * 64 + l4 * 16);
#pragma unroll
    for (int nn = 0; nn < 4; ++nn)
      bfr[nn] = *(const bf16x8*)((const char*)Bs + (wc * 64 + nn * 16 + l15) * 64 + l4 * 16);
#pragma unroll
    for (int m = 0; m < 4; ++m)
#pragma unroll
      for (int nn = 0; nn < 4; ++nn)
        acc[m][nn] = __builtin_amdgcn_mfma_f32_16x16x32_bf16(af[m], bfr[nn], acc[m][nn], 0, 0, 0);
  }
#pragma unroll
  for (int m = 0; m < 4; ++m)
#pragma unroll
    for (int nn = 0; nn < 4; ++nn)
#pragma unroll
      for (int r = 0; r < 4; ++r) {
        int row = bm + wr * 64 + m * 16 + l4 * 4 + r;
        int col = bn + wc * 64 + nn * 16 + l15;
        Y[(size_t)row * 1024 + col] = acc[m][nn][r] + bias[col];
      }
}

extern "C" void kernel_launch(void* const* d_in, const int* in_sizes, int n_in,
                              void* d_out, int out_size, void* d_ws, size_t ws_size,
                              hipStream_t stream) {
  const float* values  = (const float*)d_in[0];
  const float* keys    = (const float*)d_in[1];
  const float* queries = (const float*)d_in[2];
  const int*   mask    = (const int*)d_in[3];
  const float* Wv      = (const float*)d_in[4];
  const float* Wk      = (const float*)d_in[5];
  const float* Wq      = (const float*)d_in[6];
  const float* Wo      = (const float*)d_in[7];
  const float* bo      = (const float*)d_in[8];
  float* out = (float*)d_out;

  char* ws = (char*)d_ws;
  __hip_bfloat16* qp   = (__hip_bfloat16*)(ws);
  __hip_bfloat16* kp   = (__hip_bfloat16*)(ws + (size_t)16 * 1024 * 1024);
  __hip_bfloat16* vp   = (__hip_bfloat16*)(ws + (size_t)32 * 1024 * 1024);
  __hip_bfloat16* obuf = (__hip_bfloat16*)(ws + (size_t)48 * 1024 * 1024);
  u64*            mbts = (u64*)           (ws + (size_t)64 * 1024 * 1024);
  __hip_bfloat16* wob  = (__hip_bfloat16*)(ws + (size_t)66 * 1024 * 1024);
  __hip_bfloat16* vTp  = (__hip_bfloat16*)(ws + (size_t)80 * 1024 * 1024);

  // Q pre-scale: (1/sqrt(EMB)) * log2(e) so attn softmax runs in exp2 domain
  const float qscale = 0.03125f * 1.44269504088896340736f;

  pack_mask_k<<<dim3(N_B * SEQ), 256, 0, stream>>>(mask, mbts);
  project3_k<<<dim3(N_B * SEQ, 3), 256, 0, stream>>>(values, keys, queries,
                                                     Wv, Wk, Wq, vp, kp, qp, qscale);
  transpose_v_k<<<dim3(SEQ / 64, N_B * NH), 256, 0, stream>>>(vp, vTp);
  cvt_bf16_k<<<dim3(1024), 256, 0, stream>>>(Wo, wob);
  attn_k<<<dim3(SEQ / 64, N_B * NH), 256, 0, stream>>>(qp, kp, vTp, mbts, obuf);
  out_gemm_k<<<dim3(64, 8), 256, 0, stream>>>(obuf, wob, bo, out);
}

// Round 7
// 275.332 us; speedup vs baseline: 1.0355x; 1.0067x over previous
//
#include <hip/hip_runtime.h>
#include <hip/hip_bf16.h>

#define N_B 4
#define SEQ 2048
#define EMB 1024
#define NH  16
#define HD  64

typedef __attribute__((ext_vector_type(8))) short bf16x8;   // 8 bf16 in 4 VGPRs
typedef __attribute__((ext_vector_type(4))) short bf16x4;   // 4 bf16 in 2 VGPRs
typedef __attribute__((ext_vector_type(4))) float f32x4;
typedef unsigned int u32;
typedef unsigned long long u64;
typedef unsigned short u16;

__device__ __forceinline__ void load_lds_16B(const void* g, void* lds) {
  __builtin_amdgcn_global_load_lds(
      (const __attribute__((address_space(1))) u32*)g,
      (__attribute__((address_space(3))) u32*)lds, 16, 0, 0);
}

// pack two f32 -> two bf16 (round-to-nearest via +0x8000 before truncate)
__device__ __forceinline__ u32 pk2(float a, float b) {
  u32 au = __float_as_uint(a) + 0x8000u;
  u32 bu = __float_as_uint(b) + 0x8000u;
  return (au >> 16) | (bu & 0xFFFF0000u);
}

// ---------------- mask -> bitmask, layout [n][kb][q] (contiguous in q) ----------------
__global__ __launch_bounds__(256) void pack_mask_k(const int* __restrict__ mask,
                                                   u64* __restrict__ bits) {
  int row = blockIdx.x;                // n*SEQ + q
  int n = row >> 11, q = row & 2047;
  int lane = threadIdx.x & 63;
  int wv = threadIdx.x >> 6;
  const int* m = mask + (size_t)row * SEQ;
  for (int w = wv; w < SEQ / 64; w += 4) {
    int v = m[w * 64 + lane];
    u64 bal = __ballot(v != 0);
    if (lane == 0) bits[((size_t)n * 32 + w) * 2048 + q] = bal;
  }
}

// ---------------- fused per-head projections (q/k/v in one launch) ----------------
__global__ __launch_bounds__(256) void project3_k(const float* __restrict__ xv,
                                                  const float* __restrict__ xk,
                                                  const float* __restrict__ xq,
                                                  const float* __restrict__ Wv,
                                                  const float* __restrict__ Wk,
                                                  const float* __restrict__ Wq,
                                                  __hip_bfloat16* __restrict__ ov,
                                                  __hip_bfloat16* __restrict__ ok,
                                                  __hip_bfloat16* __restrict__ oq,
                                                  float qscale) {
  __shared__ __align__(16) float Ws4[64 * 17 * 4];  // W rows as float4, padded
  __shared__ __align__(16) float xs[1024];
  int which = blockIdx.y;
  const float* x = (which == 0) ? xv : (which == 1) ? xk : xq;
  const float* W = (which == 0) ? Wv : (which == 1) ? Wk : Wq;
  __hip_bfloat16* out = (which == 0) ? ov : (which == 1) ? ok : oq;
  float scale = (which == 2) ? qscale : 1.0f;

  int t = threadIdx.x;
  int row = blockIdx.x;            // n*SEQ + l
  int n = row >> 11, l = row & 2047;
  const float4* W4 = (const float4*)W;
#pragma unroll
  for (int i = 0; i < 4; ++i) {
    int f4 = i * 256 + t;                 // f4 = d*16 + dd4
    int d = f4 >> 4, dd4 = f4 & 15;
    *(float4*)&Ws4[(d * 17 + dd4) * 4] = W4[f4];
  }
  float4 v = ((const float4*)(x + (size_t)row * EMB))[t];
  *(float4*)&xs[t * 4] = v;
  __syncthreads();
  int d = t & 63, wv = t >> 6;
  float s[4] = {0.f, 0.f, 0.f, 0.f};
#pragma unroll
  for (int dd4 = 0; dd4 < 16; ++dd4) {
    float4 wv4 = *(const float4*)&Ws4[(d * 17 + dd4) * 4];
#pragma unroll
    for (int i = 0; i < 4; ++i) {
      float4 xv4 = *(const float4*)&xs[(i * 4 + wv) * 64 + dd4 * 4];
      s[i] += xv4.x * wv4.x + xv4.y * wv4.y + xv4.z * wv4.z + xv4.w * wv4.w;
    }
  }
#pragma unroll
  for (int i = 0; i < 4; ++i) {
    int h = i * 4 + wv;
    out[((size_t)(n * NH + h) * SEQ + l) * HD + d] = __float2bfloat16(s[i] * scale);
  }
}

// ---------------- fp32 -> bf16 copy (Wo) ----------------
__global__ __launch_bounds__(256) void cvt_bf16_k(const float* __restrict__ in,
                                                  __hip_bfloat16* __restrict__ out) {
  int i = (blockIdx.x * 256 + threadIdx.x) * 4;
  float4 v = *(const float4*)(in + i);
  out[i + 0] = __float2bfloat16(v.x);
  out[i + 1] = __float2bfloat16(v.y);
  out[i + 2] = __float2bfloat16(v.z);
  out[i + 3] = __float2bfloat16(v.w);
}

// ---------------- V transpose: vp[nh][key][d] -> vT[nh][d][granule-permuted keys] ----
// Within each 64-key tile, the 8B granule (4 keys) g of row d is stored at
// slot g ^ (d & 15). A quarter-wave ds_read_b64 of granule g across rows
// d=0..15 then covers all 32 LDS banks exactly once -> conflict-free PV reads,
// while global_load_lds staging stays linear.
__global__ __launch_bounds__(256) void transpose_v_k(const __hip_bfloat16* __restrict__ vp,
                                                     __hip_bfloat16* __restrict__ vT) {
  __shared__ __align__(16) u16 Ls[64 * 64];   // [key][d], XOR-swizzled 16B chunks
  int t = threadIdx.x;
  int kt = blockIdx.x, nh = blockIdx.y;
  const u16* src = (const u16*)(vp + ((size_t)nh * SEQ + kt * 64) * HD);
#pragma unroll
  for (int p = 0; p < 2; ++p) {
    int key = p * 32 + (t >> 3);
    int dc = t & 7;                         // 16B chunk within row
    uint4 vv = *(const uint4*)(src + key * 64 + dc * 8);
    *(uint4*)((char*)Ls + key * 128 + ((dc ^ (key & 7)) * 16)) = vv;
  }
  __syncthreads();
  u16* dst = (u16*)(vT + (size_t)nh * HD * SEQ);
#pragma unroll
  for (int p = 0; p < 2; ++p) {
    int d = p * 32 + (t >> 3);
    int kc = t & 7;                         // key chunk (8 keys = granules 2kc, 2kc+1)
    union { u16 s[8]; uint4 v4; } u;
#pragma unroll
    for (int j = 0; j < 8; ++j) {
      int key = kc * 8 + j;
      u.s[j] = *(const u16*)((const char*)Ls + key * 128 + (((d >> 3) ^ (key & 7)) * 16) + (d & 7) * 2);
    }
    u16* dstrow = dst + (size_t)d * SEQ + kt * 64;
    int x = d & 15;
    uint2 a = {u.v4.x, u.v4.y};
    uint2 b = {u.v4.z, u.v4.w};
    *(uint2*)(dstrow + (((2 * kc) ^ x) * 4))     = a;
    *(uint2*)(dstrow + (((2 * kc + 1) ^ x) * 4)) = b;
  }
}

// ---------------- flash attention: S^T swapped ops, register P, double-buffered LDS ----
// Q pre-scaled by (1/sqrt(EMB))*log2(e). Lane owns q = qb*64 + w*16 + l15.
// T3 pipeline: STAGE(t+1) issued before computing tile t; one vmcnt(0)+barrier
// per tile at iteration end -> staging latency hidden under compute.
__global__ __launch_bounds__(256) void attn_k(const __hip_bfloat16* __restrict__ qp,
                                              const __hip_bfloat16* __restrict__ kp,
                                              const __hip_bfloat16* __restrict__ vT,
                                              const u64* __restrict__ mbits,
                                              __hip_bfloat16* __restrict__ obuf) {
  __shared__ __align__(16) __hip_bfloat16 Kt[2][64 * 64];    // [key][kdim] chunk-swz
  __shared__ __align__(16) __hip_bfloat16 Vt[2][64 * 64];    // [d][key] granule-swz (pre-permuted global)
  int t = threadIdx.x, lane = t & 63, w = t >> 6;
  int qb = blockIdx.x;
  int nh = blockIdx.y;
  int n = nh >> 4, h = nh & 15;
  const __hip_bfloat16* Qg = qp + ((size_t)nh * SEQ + qb * 64) * HD;
  const char* Kg = (const char*)(kp + (size_t)nh * SEQ * HD);
  const char* Vg = (const char*)(vT + (size_t)nh * HD * SEQ);
  int l15 = lane & 15, l4 = lane >> 4;
  int e7 = l15 & 7;

  int srow = t >> 3;
  int schunk = (t & 7) ^ (srow & 7);       // K-tile source pre-swizzle (16B chunks)

  // Q B-frag: col=l15 (q=w*16+l15), k = 32c + l4*8 + j
  bf16x8 qf[2];
#pragma unroll
  for (int c = 0; c < 2; ++c)
    qf[c] = *(const bf16x8*)(Qg + (size_t)(w * 16 + l15) * HD + c * 32 + l4 * 8);

  const bf16x4 ones4 = {(short)0x3F80, (short)0x3F80, (short)0x3F80, (short)0x3F80};

  f32x4 of[4];
#pragma unroll
  for (int dt = 0; dt < 4; ++dt)
#pragma unroll
    for (int j = 0; j < 4; ++j) of[dt][j] = 0.f;
  float mrow = -1e20f, lrow = 0.f;

  int q = qb * 64 + w * 16 + l15;
  const u64* mptr = mbits + (size_t)n * 32 * 2048 + q;

  // staging base pointers (per-tile offsets added in STAGE)
  const char* gk0 = Kg + srow * 128 + schunk * 16;            // + kt*8192
  const char* gv0 = Vg + (size_t)srow * 4096 + (t & 7) * 16;  // + kt*128 (linear: global pre-permuted)

  auto STAGE = [&](int b, int kt) {
    const char* gk = gk0 + (size_t)kt * 8192;
    const char* gv = gv0 + (size_t)kt * 128;
    char* dk = (char*)&Kt[b][0] + w * 1024;
    char* dv = (char*)&Vt[b][0] + w * 1024;
    load_lds_16B(gk, dk);
    load_lds_16B(gk + 4096, dk + 4096);
    load_lds_16B(gv, dv);
    load_lds_16B(gv + (size_t)32 * 4096, dv + 4096);
  };

  // PV A-frag granule offsets: byte = row*128 + ((ct*4+l4)^l15)*8
  int voff[4];
#pragma unroll
  for (int ct = 0; ct < 4; ++ct)
    voff[ct] = (((ct * 4 + l4) ^ l15) * 8);

  // prologue
  STAGE(0, 0);
  asm volatile("s_waitcnt vmcnt(0)" ::: "memory");
  __syncthreads();

#pragma unroll 2
  for (int kt = 0; kt < SEQ / 64; ++kt) {
    int cur = kt & 1;
    if (kt < SEQ / 64 - 1) STAGE(cur ^ 1, kt + 1);
    u64 mw = mptr[(size_t)kt * 2048];
    const char* KB = (const char*)&Kt[cur][0];
    const char* VB = (const char*)&Vt[cur][0];

    // ---- S^T = K Q^T: A = K-frag (rows=keys), B = Q-frag (cols=q)
    f32x4 sf[4];
#pragma unroll
    for (int ct = 0; ct < 4; ++ct)
#pragma unroll
      for (int j = 0; j < 4; ++j) sf[ct][j] = 0.f;
#pragma unroll
    for (int c = 0; c < 2; ++c) {
#pragma unroll
      for (int ct = 0; ct < 4; ++ct) {
        int krow = ct * 16 + l15;
        bf16x8 ak = *(const bf16x8*)(KB + krow * 128 + (((c * 4 + l4) ^ e7) * 16));
        sf[ct] = __builtin_amdgcn_mfma_f32_16x16x32_bf16(ak, qf[c], sf[ct], 0, 0, 0);
      }
    }

    // ---- online softmax (scalar per lane; max over unmasked superset, exact)
    float tmax = fmaxf(
        fmaxf(fmaxf(fmaxf(sf[0][0], sf[0][1]), fmaxf(sf[0][2], sf[0][3])),
              fmaxf(fmaxf(sf[1][0], sf[1][1]), fmaxf(sf[1][2], sf[1][3]))),
        fmaxf(fmaxf(fmaxf(sf[2][0], sf[2][1]), fmaxf(sf[2][2], sf[2][3])),
              fmaxf(fmaxf(sf[3][0], sf[3][1]), fmaxf(sf[3][2], sf[3][3]))));
    if (__any(tmax > mrow)) {
      float tm = tmax;
      tm = fmaxf(tm, __shfl_xor(tm, 16));
      tm = fmaxf(tm, __shfl_xor(tm, 32));
      float mn = fmaxf(mrow, tm);
      float corr = __builtin_amdgcn_exp2f(mrow - mn);
      mrow = mn;
      lrow *= corr;
#pragma unroll
      for (int dt = 0; dt < 4; ++dt)
#pragma unroll
        for (int r = 0; r < 4; ++r) of[dt][r] *= corr;
    }
    // ---- p = exp2(s - m), mask-zero (bit 16ct + 4*l4 + r of mw), pack to bf16
    u64 m4 = mw >> (l4 * 4);
    u32 c0 = (u32)m4, c1 = (u32)(m4 >> 32);
    bf16x4 pbq[4];
#pragma unroll
    for (int ct = 0; ct < 4; ++ct) {
      u32 sel = (ct & 2) ? c1 : c0;
      u32 base = (ct & 1) ? 0x10000u : 1u;
      float p0 = __builtin_amdgcn_exp2f(sf[ct][0] - mrow);
      float p1 = __builtin_amdgcn_exp2f(sf[ct][1] - mrow);
      float p2 = __builtin_amdgcn_exp2f(sf[ct][2] - mrow);
      float p3 = __builtin_amdgcn_exp2f(sf[ct][3] - mrow);
      p0 = (sel & (base << 0)) ? p0 : 0.f;
      p1 = (sel & (base << 1)) ? p1 : 0.f;
      p2 = (sel & (base << 2)) ? p2 : 0.f;
      p3 = (sel & (base << 3)) ? p3 : 0.f;
      union { u32 u[2]; bf16x4 s; } pu;
      pu.u[0] = pk2(p0, p1);
      pu.u[1] = pk2(p2, p3);
      pbq[ct] = pu.s;
    }
    // ---- row-sum via K=16 MFMA on register P
    f32x4 rs = {0.f, 0.f, 0.f, 0.f};
#pragma unroll
    for (int ct = 0; ct < 4; ++ct)
      rs = __builtin_amdgcn_mfma_f32_16x16x16bf16_1k(ones4, pbq[ct], rs, 0, 0, 0);
    lrow += rs[0];
    // ---- O^T += V^T P : A = V^T b64 granule frags (conflict-free), B = register P
#pragma unroll
    for (int dt = 0; dt < 4; ++dt) {
      int vrow_b = (dt * 16 + l15) * 128;
#pragma unroll
      for (int ct = 0; ct < 4; ++ct) {
        bf16x4 av = *(const bf16x4*)(VB + vrow_b + voff[ct]);
        of[dt] = __builtin_amdgcn_mfma_f32_16x16x16bf16_1k(av, pbq[ct], of[dt], 0, 0, 0);
      }
    }

    if (kt < SEQ / 64 - 1) {
      asm volatile("s_waitcnt vmcnt(0)" ::: "memory");   // next-tile stage landed
      __syncthreads();                                   // visible to all waves
    }
  }
  // ---- epilogue: lane owns q; d = 16dt + 4*l4 + r (8B packed stores)
  float inv = 1.f / lrow;
  size_t obase = ((size_t)n * SEQ + q) * EMB + h * HD;
#pragma unroll
  for (int dt = 0; dt < 4; ++dt) {
    uint2 v2 = {pk2(of[dt][0] * inv, of[dt][1] * inv),
                pk2(of[dt][2] * inv, of[dt][3] * inv)};
    *(uint2*)(obuf + obase + dt * 16 + l4 * 4) = v2;
  }
}

// ---------------- output GEMM: double-buffered, chunk-swizzled ----------------
__global__ __launch_bounds__(256) void out_gemm_k(const __hip_bfloat16* __restrict__ A,
                                                  const __hip_bfloat16* __restrict__ Bw,
                                                  const float* __restrict__ bias,
                                                  float* __restrict__ Y) {
  __shared__ __align__(16) __hip_bfloat16 As[2][128 * 32];
  __shared__ __align__(16) __hip_bfloat16 Bs[2][128 * 32];
  int t = threadIdx.x, lane = t & 63, w = t >> 6;
  int l15 = lane & 15, l4 = lane >> 4;
  int bm = blockIdx.x * 128, bn = blockIdx.y * 128;
  int wr = w >> 1, wc = w & 1;
  f32x4 acc[4][4];
#pragma unroll
  for (int m = 0; m < 4; ++m)
#pragma unroll
    for (int nn = 0; nn < 4; ++nn)
#pragma unroll
      for (int j = 0; j < 4; ++j) acc[m][nn][j] = 0.f;

  int srow = t >> 2;                        // LDS row 0..63 (row stride 64B)
  int schunk = (t & 3) ^ (srow & 3);        // source 16B chunk pre-swizzle

  auto STAGE = [&](int b, int kt) {
    const char* ga = (const char*)(A + (size_t)(bm + srow) * 1024 + kt * 32) + schunk * 16;
    char* da = (char*)&As[b][0] + w * 1024;
    load_lds_16B(ga, da);
    load_lds_16B(ga + (size_t)64 * 2048, da + 4096);   // rows +64: same (row&3)
    const char* gb = (const char*)(Bw + (size_t)(bn + srow) * 1024 + kt * 32) + schunk * 16;
    char* db = (char*)&Bs[b][0] + w * 1024;
    load_lds_16B(gb, db);
    load_lds_16B(gb + (size_t)64 * 2048, db + 4096);
  };

  STAGE(0, 0);
  asm volatile("s_waitcnt vmcnt(0)" ::: "memory");
  __syncthreads();

#pragma unroll 2
  for (int kt = 0; kt < 32; ++kt) {
    int cur = kt & 1;
    if (kt < 31) STAGE(cur ^ 1, kt + 1);
    const char* AB = (const char*)&As[cur][0];
    const char* BB = (const char*)&Bs[cur][0];
    bf16x8 af[4], bfr[4];
#pragma unroll
    for (int m = 0; m < 4; ++m) {
      int arow = wr * 64 + m * 16 + l15;
      af[m] = *(const bf16x8*)(AB + arow * 64 + ((l4 ^ (arow & 3)) * 16));
    }
#pragma unroll
    for (int nn = 0; nn < 4; ++nn) {
      int brow = wc * 64 + nn * 16 + l15;
      bfr[nn] = *(const bf16x8*)(BB + brow * 64 + ((l4 ^ (brow & 3)) * 16));
    }
#pragma unroll
    for (int m = 0; m < 4; ++m)
#pragma unroll
      for (int nn = 0; nn < 4; ++nn)
        acc[m][nn] = __builtin_amdgcn_mfma_f32_16x16x32_bf16(af[m], bfr[nn], acc[m][nn], 0, 0, 0);
    if (kt < 31) {
      asm volatile("s_waitcnt vmcnt(0)" ::: "memory");
      __syncthreads();
    }
  }
#pragma unroll
  for (int m = 0; m < 4; ++m)
#pragma unroll
    for (int nn = 0; nn < 4; ++nn)
#pragma unroll
      for (int r = 0; r < 4; ++r) {
        int row = bm + wr * 64 + m * 16 + l4 * 4 + r;
        int col = bn + wc * 64 + nn * 16 + l15;
        Y[(size_t)row * 1024 + col] = acc[m][nn][r] + bias[col];
      }
}

extern "C" void kernel_launch(void* const* d_in, const int* in_sizes, int n_in,
                              void* d_out, int out_size, void* d_ws, size_t ws_size,
                              hipStream_t stream) {
  const float* values  = (const float*)d_in[0];
  const float* keys    = (const float*)d_in[1];
  const float* queries = (const float*)d_in[2];
  const int*   mask    = (const int*)d_in[3];
  const float* Wv      = (const float*)d_in[4];
  const float* Wk      = (const float*)d_in[5];
  const float* Wq      = (const float*)d_in[6];
  const float* Wo      = (const float*)d_in[7];
  const float* bo      = (const float*)d_in[8];
  float* out = (float*)d_out;

  char* ws = (char*)d_ws;
  __hip_bfloat16* qp   = (__hip_bfloat16*)(ws);
  __hip_bfloat16* kp   = (__hip_bfloat16*)(ws + (size_t)16 * 1024 * 1024);
  __hip_bfloat16* vp   = (__hip_bfloat16*)(ws + (size_t)32 * 1024 * 1024);
  __hip_bfloat16* obuf = (__hip_bfloat16*)(ws + (size_t)48 * 1024 * 1024);
  u64*            mbts = (u64*)           (ws + (size_t)64 * 1024 * 1024);
  __hip_bfloat16* wob  = (__hip_bfloat16*)(ws + (size_t)66 * 1024 * 1024);
  __hip_bfloat16* vTp  = (__hip_bfloat16*)(ws + (size_t)80 * 1024 * 1024);

  // Q pre-scale: (1/sqrt(EMB)) * log2(e) so attn softmax runs in exp2 domain
  const float qscale = 0.03125f * 1.44269504088896340736f;

  pack_mask_k<<<dim3(N_B * SEQ), 256, 0, stream>>>(mask, mbts);
  project3_k<<<dim3(N_B * SEQ, 3), 256, 0, stream>>>(values, keys, queries,
                                                     Wv, Wk, Wq, vp, kp, qp, qscale);
  transpose_v_k<<<dim3(SEQ / 64, N_B * NH), 256, 0, stream>>>(vp, vTp);
  cvt_bf16_k<<<dim3(1024), 256, 0, stream>>>(Wo, wob);
  attn_k<<<dim3(SEQ / 64, N_B * NH), 256, 0, stream>>>(qp, kp, vTp, mbts, obuf);
  out_gemm_k<<<dim3(64, 8), 256, 0, stream>>>(obuf, wob, bo, out);
}

// Round 8
// 263.340 us; speedup vs baseline: 1.0827x; 1.0455x over previous
//
#include <hip/hip_runtime.h>
#include <hip/hip_bf16.h>

#define N_B 4
#define SEQ 2048
#define EMB 1024
#define NH  16
#define HD  64

typedef __attribute__((ext_vector_type(8))) short bf16x8;   // 8 bf16 in 4 VGPRs
typedef __attribute__((ext_vector_type(4))) short bf16x4;   // 4 bf16 in 2 VGPRs
typedef __attribute__((ext_vector_type(4))) float f32x4;
typedef unsigned int u32;
typedef unsigned long long u64;
typedef unsigned short u16;

__device__ __forceinline__ void load_lds_16B(const void* g, void* lds) {
  __builtin_amdgcn_global_load_lds(
      (const __attribute__((address_space(1))) u32*)g,
      (__attribute__((address_space(3))) u32*)lds, 16, 0, 0);
}

// pack two f32 -> two bf16 (round-to-nearest via +0x8000 before truncate)
__device__ __forceinline__ u32 pk2(float a, float b) {
  u32 au = __float_as_uint(a) + 0x8000u;
  u32 bu = __float_as_uint(b) + 0x8000u;
  return (au >> 16) | (bu & 0xFFFF0000u);
}

__device__ __forceinline__ float m3(float a, float b, float c) {
  return fmaxf(fmaxf(a, b), c);   // clang fuses to v_max3_f32
}

// ---------------- mask -> bitmask, layout [n][kb][q] (contiguous in q) ----------------
__global__ __launch_bounds__(256) void pack_mask_k(const int* __restrict__ mask,
                                                   u64* __restrict__ bits) {
  int row = blockIdx.x;                // n*SEQ + q
  int n = row >> 11, q = row & 2047;
  int lane = threadIdx.x & 63;
  int wv = threadIdx.x >> 6;
  const int* m = mask + (size_t)row * SEQ;
  for (int w = wv; w < SEQ / 64; w += 4) {
    int v = m[w * 64 + lane];
    u64 bal = __ballot(v != 0);
    if (lane == 0) bits[((size_t)n * 32 + w) * 2048 + q] = bal;
  }
}

// ---------------- fused per-head projections (q/k/v in one launch) ----------------
__global__ __launch_bounds__(256) void project3_k(const float* __restrict__ xv,
                                                  const float* __restrict__ xk,
                                                  const float* __restrict__ xq,
                                                  const float* __restrict__ Wv,
                                                  const float* __restrict__ Wk,
                                                  const float* __restrict__ Wq,
                                                  __hip_bfloat16* __restrict__ ov,
                                                  __hip_bfloat16* __restrict__ ok,
                                                  __hip_bfloat16* __restrict__ oq,
                                                  float qscale) {
  __shared__ __align__(16) float Ws4[64 * 17 * 4];  // W rows as float4, padded
  __shared__ __align__(16) float xs[1024];
  int which = blockIdx.y;
  const float* x = (which == 0) ? xv : (which == 1) ? xk : xq;
  const float* W = (which == 0) ? Wv : (which == 1) ? Wk : Wq;
  __hip_bfloat16* out = (which == 0) ? ov : (which == 1) ? ok : oq;
  float scale = (which == 2) ? qscale : 1.0f;

  int t = threadIdx.x;
  int row = blockIdx.x;            // n*SEQ + l
  int n = row >> 11, l = row & 2047;
  const float4* W4 = (const float4*)W;
#pragma unroll
  for (int i = 0; i < 4; ++i) {
    int f4 = i * 256 + t;                 // f4 = d*16 + dd4
    int d = f4 >> 4, dd4 = f4 & 15;
    *(float4*)&Ws4[(d * 17 + dd4) * 4] = W4[f4];
  }
  float4 v = ((const float4*)(x + (size_t)row * EMB))[t];
  *(float4*)&xs[t * 4] = v;
  __syncthreads();
  int d = t & 63, wv = t >> 6;
  float s[4] = {0.f, 0.f, 0.f, 0.f};
#pragma unroll
  for (int dd4 = 0; dd4 < 16; ++dd4) {
    float4 wv4 = *(const float4*)&Ws4[(d * 17 + dd4) * 4];
#pragma unroll
    for (int i = 0; i < 4; ++i) {
      float4 xv4 = *(const float4*)&xs[(i * 4 + wv) * 64 + dd4 * 4];
      s[i] += xv4.x * wv4.x + xv4.y * wv4.y + xv4.z * wv4.z + xv4.w * wv4.w;
    }
  }
#pragma unroll
  for (int i = 0; i < 4; ++i) {
    int h = i * 4 + wv;
    out[((size_t)(n * NH + h) * SEQ + l) * HD + d] = __float2bfloat16(s[i] * scale);
  }
}

// ---------------- fp32 -> bf16 copy (Wo) ----------------
__global__ __launch_bounds__(256) void cvt_bf16_k(const float* __restrict__ in,
                                                  __hip_bfloat16* __restrict__ out) {
  int i = (blockIdx.x * 256 + threadIdx.x) * 4;
  float4 v = *(const float4*)(in + i);
  out[i + 0] = __float2bfloat16(v.x);
  out[i + 1] = __float2bfloat16(v.y);
  out[i + 2] = __float2bfloat16(v.z);
  out[i + 3] = __float2bfloat16(v.w);
}

// ---------------- V transpose: vp[nh][key][d] -> vT[nh][d][granule-permuted keys] ----
__global__ __launch_bounds__(256) void transpose_v_k(const __hip_bfloat16* __restrict__ vp,
                                                     __hip_bfloat16* __restrict__ vT) {
  __shared__ __align__(16) u16 Ls[64 * 64];   // [key][d], XOR-swizzled 16B chunks
  int t = threadIdx.x;
  int kt = blockIdx.x, nh = blockIdx.y;
  const u16* src = (const u16*)(vp + ((size_t)nh * SEQ + kt * 64) * HD);
#pragma unroll
  for (int p = 0; p < 2; ++p) {
    int key = p * 32 + (t >> 3);
    int dc = t & 7;                         // 16B chunk within row
    uint4 vv = *(const uint4*)(src + key * 64 + dc * 8);
    *(uint4*)((char*)Ls + key * 128 + ((dc ^ (key & 7)) * 16)) = vv;
  }
  __syncthreads();
  u16* dst = (u16*)(vT + (size_t)nh * HD * SEQ);
#pragma unroll
  for (int p = 0; p < 2; ++p) {
    int d = p * 32 + (t >> 3);
    int kc = t & 7;                         // key chunk (8 keys = granules 2kc, 2kc+1)
    union { u16 s[8]; uint4 v4; } u;
#pragma unroll
    for (int j = 0; j < 8; ++j) {
      int key = kc * 8 + j;
      u.s[j] = *(const u16*)((const char*)Ls + key * 128 + (((d >> 3) ^ (key & 7)) * 16) + (d & 7) * 2);
    }
    u16* dstrow = dst + (size_t)d * SEQ + kt * 64;
    int x = d & 15;
    uint2 a = {u.v4.x, u.v4.y};
    uint2 b = {u.v4.z, u.v4.w};
    *(uint2*)(dstrow + (((2 * kc) ^ x) * 4))     = a;
    *(uint2*)(dstrow + (((2 * kc + 1) ^ x) * 4)) = b;
  }
}

// ---------------- flash attention ----------------
// S^T swapped ops, register P, dbuf LDS, -m-seeded QK accumulator, defer-max
// THR=8 (rescale branch ~never taken), cross-tile MFMA row-sum, mask prefetch.
__global__ __launch_bounds__(256) void attn_k(const __hip_bfloat16* __restrict__ qp,
                                              const __hip_bfloat16* __restrict__ kp,
                                              const __hip_bfloat16* __restrict__ vT,
                                              const u64* __restrict__ mbits,
                                              __hip_bfloat16* __restrict__ obuf) {
  __shared__ __align__(16) __hip_bfloat16 Kt[2][64 * 64];    // [key][kdim] chunk-swz
  __shared__ __align__(16) __hip_bfloat16 Vt[2][64 * 64];    // [d][key] granule-swz
  int t = threadIdx.x, lane = t & 63, w = t >> 6;
  int qb = blockIdx.x;
  int nh = blockIdx.y;
  int n = nh >> 4, h = nh & 15;
  const __hip_bfloat16* Qg = qp + ((size_t)nh * SEQ + qb * 64) * HD;
  const char* Kg = (const char*)(kp + (size_t)nh * SEQ * HD);
  const char* Vg = (const char*)(vT + (size_t)nh * HD * SEQ);
  int l15 = lane & 15, l4 = lane >> 4;
  int e7 = l15 & 7;

  int srow = t >> 3;
  int schunk = (t & 7) ^ (srow & 7);       // K-tile source pre-swizzle (16B chunks)

  // Q B-frag: col=l15 (q=w*16+l15), k = 32c + l4*8 + j
  bf16x8 qf[2];
#pragma unroll
  for (int c = 0; c < 2; ++c)
    qf[c] = *(const bf16x8*)(Qg + (size_t)(w * 16 + l15) * HD + c * 32 + l4 * 8);

  const bf16x4 ones4 = {(short)0x3F80, (short)0x3F80, (short)0x3F80, (short)0x3F80};

  f32x4 of[4];
#pragma unroll
  for (int dt = 0; dt < 4; ++dt)
#pragma unroll
    for (int j = 0; j < 4; ++j) of[dt][j] = 0.f;
  f32x4 rs = {0.f, 0.f, 0.f, 0.f};   // cross-tile row-sum accumulator (all rows equal)
  float negm = 0.f;                  // = -m; m starts at 0 (defer-max reference)

  int q = qb * 64 + w * 16 + l15;
  const u64* mptr = mbits + (size_t)n * 32 * 2048 + q;

  // staging base pointers (per-tile offsets added in STAGE)
  const char* gk0 = Kg + srow * 128 + schunk * 16;            // + kt*8192
  const char* gv0 = Vg + (size_t)srow * 4096 + (t & 7) * 16;  // + kt*128

  auto STAGE = [&](int b, int kt) {
    const char* gk = gk0 + (size_t)kt * 8192;
    const char* gv = gv0 + (size_t)kt * 128;
    char* dk = (char*)&Kt[b][0] + w * 1024;
    char* dv = (char*)&Vt[b][0] + w * 1024;
    load_lds_16B(gk, dk);
    load_lds_16B(gk + 4096, dk + 4096);
    load_lds_16B(gv, dv);
    load_lds_16B(gv + (size_t)32 * 4096, dv + 4096);
  };

  // PV A-frag granule offsets: byte = row*128 + ((ct*4+l4)^l15)*8
  int voff[4];
#pragma unroll
  for (int ct = 0; ct < 4; ++ct)
    voff[ct] = (((ct * 4 + l4) ^ l15) * 8);

  // prologue
  STAGE(0, 0);
  u64 mw = mptr[0];
  asm volatile("s_waitcnt vmcnt(0)" ::: "memory");
  __syncthreads();

#pragma unroll 2
  for (int kt = 0; kt < SEQ / 64; ++kt) {
    int cur = kt & 1;
    u64 mw_nxt = 0;
    if (kt < SEQ / 64 - 1) {
      STAGE(cur ^ 1, kt + 1);
      mw_nxt = mptr[(size_t)(kt + 1) * 2048];   // prefetch next tile's mask word
    }
    const char* KB = (const char*)&Kt[cur][0];
    const char* VB = (const char*)&Vt[cur][0];

    // ---- S^T = K Q^T, accumulator seeded with -m => sf = s - m after MFMA
    f32x4 sf[4];
#pragma unroll
    for (int ct = 0; ct < 4; ++ct)
#pragma unroll
      for (int j = 0; j < 4; ++j) sf[ct][j] = negm;
#pragma unroll
    for (int c = 0; c < 2; ++c) {
#pragma unroll
      for (int ct = 0; ct < 4; ++ct) {
        int krow = ct * 16 + l15;
        bf16x8 ak = *(const bf16x8*)(KB + krow * 128 + (((c * 4 + l4) ^ e7) * 16));
        sf[ct] = __builtin_amdgcn_mfma_f32_16x16x32_bf16(ak, qf[c], sf[ct], 0, 0, 0);
      }
    }

    // ---- defer-max: rescale only if some lane's tile max exceeds THR=8
    float t0 = m3(sf[0][0], sf[0][1], sf[0][2]);
    float t1 = m3(sf[0][3], sf[1][0], sf[1][1]);
    float t2 = m3(sf[1][2], sf[1][3], sf[2][0]);
    float t3 = m3(sf[2][1], sf[2][2], sf[2][3]);
    float t4 = m3(sf[3][0], sf[3][1], sf[3][2]);
    float tmax = fmaxf(m3(t0, t1, t2), m3(t3, t4, sf[3][3]));
    if (__any(tmax > 8.f)) {
      float tm = fmaxf(tmax, __shfl_xor(tmax, 16));
      tm = fmaxf(tm, __shfl_xor(tm, 32));
      float d = fmaxf(tm, 0.f);                 // per-q delta (0 if no new max)
      float corr = __builtin_amdgcn_exp2f(-d);
      negm -= d;
#pragma unroll
      for (int j = 0; j < 4; ++j) rs[j] *= corr;
#pragma unroll
      for (int dt = 0; dt < 4; ++dt)
#pragma unroll
        for (int r = 0; r < 4; ++r) of[dt][r] *= corr;
#pragma unroll
      for (int ct = 0; ct < 4; ++ct)
#pragma unroll
        for (int r = 0; r < 4; ++r) sf[ct][r] -= d;
    }
    // ---- p = exp2(sf) (<= 2^8), mask-zero (bit 16ct + 4*l4 + r), pack to bf16
    u64 m4 = mw >> (l4 * 4);
    u32 c0 = (u32)m4, c1 = (u32)(m4 >> 32);
    bf16x4 pbq[4];
#pragma unroll
    for (int ct = 0; ct < 4; ++ct) {
      u32 sel = (ct & 2) ? c1 : c0;
      u32 base = (ct & 1) ? 0x10000u : 1u;
      float p0 = __builtin_amdgcn_exp2f(sf[ct][0]);
      float p1 = __builtin_amdgcn_exp2f(sf[ct][1]);
      float p2 = __builtin_amdgcn_exp2f(sf[ct][2]);
      float p3 = __builtin_amdgcn_exp2f(sf[ct][3]);
      p0 = (sel & (base << 0)) ? p0 : 0.f;
      p1 = (sel & (base << 1)) ? p1 : 0.f;
      p2 = (sel & (base << 2)) ? p2 : 0.f;
      p3 = (sel & (base << 3)) ? p3 : 0.f;
      union { u32 u[2]; bf16x4 s; } pu;
      pu.u[0] = pk2(p0, p1);
      pu.u[1] = pk2(p2, p3);
      pbq[ct] = pu.s;
    }
    // ---- row-sum accumulates across tiles (A = ones => all C rows identical)
#pragma unroll
    for (int ct = 0; ct < 4; ++ct)
      rs = __builtin_amdgcn_mfma_f32_16x16x16bf16_1k(ones4, pbq[ct], rs, 0, 0, 0);
    // ---- O^T += V^T P : A = V^T b64 granule frags (conflict-free), B = register P
#pragma unroll
    for (int dt = 0; dt < 4; ++dt) {
      int vrow_b = (dt * 16 + l15) * 128;
#pragma unroll
      for (int ct = 0; ct < 4; ++ct) {
        bf16x4 av = *(const bf16x4*)(VB + vrow_b + voff[ct]);
        of[dt] = __builtin_amdgcn_mfma_f32_16x16x16bf16_1k(av, pbq[ct], of[dt], 0, 0, 0);
      }
    }

    mw = mw_nxt;
    if (kt < SEQ / 64 - 1) {
      asm volatile("s_waitcnt vmcnt(0)" ::: "memory");   // next-tile stage landed
      __syncthreads();
    }
  }
  // ---- epilogue: lane owns q; d = 16dt + 4*l4 + r (8B packed stores)
  float inv = 1.f / rs[0];
  size_t obase = ((size_t)n * SEQ + q) * EMB + h * HD;
#pragma unroll
  for (int dt = 0; dt < 4; ++dt) {
    uint2 v2 = {pk2(of[dt][0] * inv, of[dt][1] * inv),
                pk2(of[dt][2] * inv, of[dt][3] * inv)};
    *(uint2*)(obuf + obase + dt * 16 + l4 * 4) = v2;
  }
}

// ---------------- output GEMM: double-buffered, chunk-swizzled ----------------
__global__ __launch_bounds__(256) void out_gemm_k(const __hip_bfloat16* __restrict__ A,
                                                  const __hip_bfloat16* __restrict__ Bw,
                                                  const float* __restrict__ bias,
                                                  float* __restrict__ Y) {
  __shared__ __align__(16) __hip_bfloat16 As[2][128 * 32];
  __shared__ __align__(16) __hip_bfloat16 Bs[2][128 * 32];
  int t = threadIdx.x, lane = t & 63, w = t >> 6;
  int l15 = lane & 15, l4 = lane >> 4;
  int bm = blockIdx.x * 128, bn = blockIdx.y * 128;
  int wr = w >> 1, wc = w & 1;
  f32x4 acc[4][4];
#pragma unroll
  for (int m = 0; m < 4; ++m)
#pragma unroll
    for (int nn = 0; nn < 4; ++nn)
#pragma unroll
      for (int j = 0; j < 4; ++j) acc[m][nn][j] = 0.f;

  int srow = t >> 2;                        // LDS row 0..63 (row stride 64B)
  int schunk = (t & 3) ^ (srow & 3);        // source 16B chunk pre-swizzle

  auto STAGE = [&](int b, int kt) {
    const char* ga = (const char*)(A + (size_t)(bm + srow) * 1024 + kt * 32) + schunk * 16;
    char* da = (char*)&As[b][0] + w * 1024;
    load_lds_16B(ga, da);
    load_lds_16B(ga + (size_t)64 * 2048, da + 4096);   // rows +64: same (row&3)
    const char* gb = (const char*)(Bw + (size_t)(bn + srow) * 1024 + kt * 32) + schunk * 16;
    char* db = (char*)&Bs[b][0] + w * 1024;
    load_lds_16B(gb, db);
    load_lds_16B(gb + (size_t)64 * 2048, db + 4096);
  };

  STAGE(0, 0);
  asm volatile("s_waitcnt vmcnt(0)" ::: "memory");
  __syncthreads();

#pragma unroll 2
  for (int kt = 0; kt < 32; ++kt) {
    int cur = kt & 1;
    if (kt < 31) STAGE(cur ^ 1, kt + 1);
    const char* AB = (const char*)&As[cur][0];
    const char* BB = (const char*)&Bs[cur][0];
    bf16x8 af[4], bfr[4];
#pragma unroll
    for (int m = 0; m < 4; ++m) {
      int arow = wr * 64 + m * 16 + l15;
      af[m] = *(const bf16x8*)(AB + arow * 64 + ((l4 ^ (arow & 3)) * 16));
    }
#pragma unroll
    for (int nn = 0; nn < 4; ++nn) {
      int brow = wc * 64 + nn * 16 + l15;
      bfr[nn] = *(const bf16x8*)(BB + brow * 64 + ((l4 ^ (brow & 3)) * 16));
    }
#pragma unroll
    for (int m = 0; m < 4; ++m)
#pragma unroll
      for (int nn = 0; nn < 4; ++nn)
        acc[m][nn] = __builtin_amdgcn_mfma_f32_16x16x32_bf16(af[m], bfr[nn], acc[m][nn], 0, 0, 0);
    if (kt < 31) {
      asm volatile("s_waitcnt vmcnt(0)" ::: "memory");
      __syncthreads();
    }
  }
#pragma unroll
  for (int m = 0; m < 4; ++m)
#pragma unroll
    for (int nn = 0; nn < 4; ++nn)
#pragma unroll
      for (int r = 0; r < 4; ++r) {
        int row = bm + wr * 64 + m * 16 + l4 * 4 + r;
        int col = bn + wc * 64 + nn * 16 + l15;
        Y[(size_t)row * 1024 + col] = acc[m][nn][r] + bias[col];
      }
}

extern "C" void kernel_launch(void* const* d_in, const int* in_sizes, int n_in,
                              void* d_out, int out_size, void* d_ws, size_t ws_size,
                              hipStream_t stream) {
  const float* values  = (const float*)d_in[0];
  const float* keys    = (const float*)d_in[1];
  const float* queries = (const float*)d_in[2];
  const int*   mask    = (const int*)d_in[3];
  const float* Wv      = (const float*)d_in[4];
  const float* Wk      = (const float*)d_in[5];
  const float* Wq      = (const float*)d_in[6];
  const float* Wo      = (const float*)d_in[7];
  const float* bo      = (const float*)d_in[8];
  float* out = (float*)d_out;

  char* ws = (char*)d_ws;
  __hip_bfloat16* qp   = (__hip_bfloat16*)(ws);
  __hip_bfloat16* kp   = (__hip_bfloat16*)(ws + (size_t)16 * 1024 * 1024);
  __hip_bfloat16* vp   = (__hip_bfloat16*)(ws + (size_t)32 * 1024 * 1024);
  __hip_bfloat16* obuf = (__hip_bfloat16*)(ws + (size_t)48 * 1024 * 1024);
  u64*            mbts = (u64*)           (ws + (size_t)64 * 1024 * 1024);
  __hip_bfloat16* wob  = (__hip_bfloat16*)(ws + (size_t)66 * 1024 * 1024);
  __hip_bfloat16* vTp  = (__hip_bfloat16*)(ws + (size_t)80 * 1024 * 1024);

  // Q pre-scale: (1/sqrt(EMB)) * log2(e) so attn softmax runs in exp2 domain
  const float qscale = 0.03125f * 1.44269504088896340736f;

  pack_mask_k<<<dim3(N_B * SEQ), 256, 0, stream>>>(mask, mbts);
  project3_k<<<dim3(N_B * SEQ, 3), 256, 0, stream>>>(values, keys, queries,
                                                     Wv, Wk, Wq, vp, kp, qp, qscale);
  transpose_v_k<<<dim3(SEQ / 64, N_B * NH), 256, 0, stream>>>(vp, vTp);
  cvt_bf16_k<<<dim3(1024), 256, 0, stream>>>(Wo, wob);
  attn_k<<<dim3(SEQ / 64, N_B * NH), 256, 0, stream>>>(qp, kp, vTp, mbts, obuf);
  out_gemm_k<<<dim3(64, 8), 256, 0, stream>>>(obuf, wob, bo, out);
}